// Round 1
// baseline (2996.586 us; speedup 1.0000x reference)
//
#include <hip/hip_runtime.h>
#include <cstdint>

#define HID 250
#define NIN 128
#define BATCH 512
#define N1 (BATCH * HID)          // 128000 layer-1/2 neuron-chains
#define T_TOTAL 1000
#define OUT_HALF 1024000          // 1000*512*2 floats per output tensor

// ---------------------------------------------------------------------------
// pad_w: one-time prep. W1p[128][256], W2p[250][256] — column-padded copies
// (cols 250..255 zero). Gives the GEMM k-loops branch-free, 16B-aligned
// float4 loads (W stride 250 floats is 8B-misaligned for odd k otherwise).
// ---------------------------------------------------------------------------
__global__ __launch_bounds__(256) void pad_w(
    const float* __restrict__ W1, const float* __restrict__ W2,
    float* __restrict__ W1p, float* __restrict__ W2p)
{
    const int i = blockIdx.x * 256 + threadIdx.x;   // grid 250*256 = 64000
    if (i < 128 * 256) {
        const int k = i >> 8, c = i & 255;
        W1p[i] = (c < HID) ? W1[k * HID + c] : 0.0f;
    }
    if (i < 250 * 256) {
        const int k = i >> 8, c = i & 255;
        W2p[i] = (c < HID) ? W2[k * HID + c] : 0.0f;
    }
}

// ---------------------------------------------------------------------------
// GEMM1 v3: register-tiled 64x256 (250 used), 256 thr. vs v2: W read from
// padded W1p[128][256] -> inner k-loop is 4 branch-free aligned float4 loads
// at immediate offsets (no divergent ci<14 guard, no odd-k misalignment),
// unroll 2 so next-k loads pipeline under current-k FMAs.
// Numerics: per output element single accumulator, fused fmaf, k ascending —
// bit-identical to v2 (padded cols compute garbage-zero, never stored).
// ---------------------------------------------------------------------------
__global__ __launch_bounds__(256, 4) void gemm1_v3(
    const float* __restrict__ x,    // [M][128]
    const float* __restrict__ W1p,  // [128][256] padded
    const float* __restrict__ b1,   // [250]
    float* __restrict__ cur,        // [M][250]
    int M)
{
#pragma clang fp contract(off)
    __shared__ __align__(16) float xT[128 * 68];   // 34816 B
    const int tid  = threadIdx.x;
    const int lane = tid & 63, wave = tid >> 6;
    const long rowBase = (long)blockIdx.x * 64;

    // stage x[rowBase..+64][0..128) transposed: LDS writes conflict-free
    const float* xb = x + rowBase * NIN;
    #pragma unroll
    for (int i = 0; i < 8; ++i) {
        const int kq = i * 4 + wave;
        const float4 v = *(const float4*)(xb + (long)lane * NIN + kq * 4);
        xT[(4 * kq + 0) * 68 + lane] = v.x;
        xT[(4 * kq + 1) * 68 + lane] = v.y;
        xT[(4 * kq + 2) * 68 + lane] = v.z;
        xT[(4 * kq + 3) * 68 + lane] = v.w;
    }
    __syncthreads();

    const int ri = tid >> 4;   // 0..15 -> rows 4ri..4ri+3
    const int ci = tid & 15;   // 0..15 -> col quads 64j + 4ci

    float acc[4][16];
    #pragma unroll
    for (int r = 0; r < 4; ++r)
        #pragma unroll
        for (int c = 0; c < 16; ++c) acc[r][c] = 0.0f;

    #pragma unroll 2
    for (int k = 0; k < NIN; ++k) {
        const float4 a = *(const float4*)&xT[k * 68 + 4 * ri];  // broadcast
        const float* wr = W1p + (k << 8) + 4 * ci;
        const float4 wv0 = *(const float4*)(wr);
        const float4 wv1 = *(const float4*)(wr + 64);
        const float4 wv2 = *(const float4*)(wr + 128);
        const float4 wv3 = *(const float4*)(wr + 192);
        const float w[16] = {wv0.x, wv0.y, wv0.z, wv0.w,
                             wv1.x, wv1.y, wv1.z, wv1.w,
                             wv2.x, wv2.y, wv2.z, wv2.w,
                             wv3.x, wv3.y, wv3.z, wv3.w};
        const float av[4] = {a.x, a.y, a.z, a.w};
        #pragma unroll
        for (int r = 0; r < 4; ++r)
            #pragma unroll
            for (int c = 0; c < 16; ++c)
                acc[r][c] = __builtin_fmaf(av[r], w[c], acc[r][c]);
    }

    // epilogue: +bias (separately rounded), float2 stores (250 even -> 8B ok)
    #pragma unroll
    for (int j = 0; j < 4; ++j) {
        #pragma unroll
        for (int p = 0; p < 2; ++p) {
            const int cp = 64 * j + 4 * ci + 2 * p;
            if (cp < HID) {
                const float b0 = b1[cp], b1v = b1[cp + 1];
                #pragma unroll
                for (int r = 0; r < 4; ++r) {
                    const long row = rowBase + 4 * ri + r;
                    float2 o;
                    o.x = acc[r][4*j + 2*p]     + b0;
                    o.y = acc[r][4*j + 2*p + 1] + b1v;
                    *(float2*)(cur + row * HID + cp) = o;
                }
            }
        }
    }
}

// ---------------------------------------------------------------------------
// LIF scan layers 1/2 (unchanged): unroll x4, loads hoisted ahead of the
// dependent recurrence.
// ---------------------------------------------------------------------------
__global__ __launch_bounds__(256) void scan_f32(
    const float* __restrict__ cur,   // [Tc][N1]
    uint8_t* __restrict__ spk,       // [Tc][N1]
    float* __restrict__ state,       // [N1]
    int Tc)
{
#pragma clang fp contract(off)
    const int n = blockIdx.x * 256 + threadIdx.x;   // grid = 500*256 == N1
    float m = state[n];
    int t = 0;
    for (; t + 4 <= Tc; t += 4) {
        const long base = (long)t * N1 + n;
        const float c0 = cur[base];
        const float c1 = cur[base + N1];
        const float c2 = cur[base + 2L * N1];
        const float c3 = cur[base + 3L * N1];
        float r, tmp;
        r = (m > 1.0f) ? 1.0f : 0.0f; tmp = 0.9f * m; tmp = tmp + c0; m = tmp - r;
        spk[base]           = (m > 1.0f) ? (uint8_t)1 : (uint8_t)0;
        r = (m > 1.0f) ? 1.0f : 0.0f; tmp = 0.9f * m; tmp = tmp + c1; m = tmp - r;
        spk[base + N1]      = (m > 1.0f) ? (uint8_t)1 : (uint8_t)0;
        r = (m > 1.0f) ? 1.0f : 0.0f; tmp = 0.9f * m; tmp = tmp + c2; m = tmp - r;
        spk[base + 2L * N1] = (m > 1.0f) ? (uint8_t)1 : (uint8_t)0;
        r = (m > 1.0f) ? 1.0f : 0.0f; tmp = 0.9f * m; tmp = tmp + c3; m = tmp - r;
        spk[base + 3L * N1] = (m > 1.0f) ? (uint8_t)1 : (uint8_t)0;
    }
    for (; t < Tc; ++t) {
        const long base = (long)t * N1 + n;
        const float c = cur[base];
        const float r = (m > 1.0f) ? 1.0f : 0.0f;
        float tmp = 0.9f * m; tmp = tmp + c; m = tmp - r;
        spk[base] = (m > 1.0f) ? (uint8_t)1 : (uint8_t)0;
    }
    state[n] = m;
}

// ---------------------------------------------------------------------------
// GEMM2 v3: LDS-staged W2 column-quarter. Block = 256 thr, blockIdx = 4*tile+q:
// stages W2p cols [64q,64q+64) for ALL 250 k (64 KB LDS -> 2 blocks/CU), then
// each wave independently processes 32 of the tile's 128 rows: spike bytes ->
// __ballot masks (SGPRs), scalar-ctz walk in 4-deep batches so 4 ds_read_b32
// are in flight; next row's spike bytes prefetched during the current walk.
// W2 operand traffic moves from L2 (~135 GB/s/CU, zero reuse) to LDS.
// Numerics: per output single accumulator, plain adds ascending k, bias added
// once at the end — bit-identical to v2's list walk.
// ---------------------------------------------------------------------------
__global__ __launch_bounds__(256, 2) void gemm2_v3(
    const uint8_t* __restrict__ s,   // [M][250] spikes 0/1
    const float* __restrict__ W2p,   // [250][256] padded
    const float* __restrict__ b2,    // [250]
    float* __restrict__ cur,         // [M][250]
    int M)
{
#pragma clang fp contract(off)
    __shared__ __align__(16) float Wq[250 * 64];   // 64000 B
    const int tid  = threadIdx.x;
    const int lane = tid & 63, wave = tid >> 6;
    const int q    = blockIdx.x & 3;               // column quarter
    const long r0  = (long)(blockIdx.x >> 2) * 128;

    // stage quarter: Wq[k][c] = W2p[k][64q + c], 4000 float4s over 256 thr
    {
        const float* src = W2p + q * 64;
        #pragma unroll
        for (int i = 0; i < 16; ++i) {
            const int idx = i * 256 + tid;         // 0..4095
            if (idx < 4000) {
                const int k = idx >> 4, c4 = (idx & 15) * 4;
                *(float4*)&Wq[k * 64 + c4] = *(const float4*)(src + k * 256 + c4);
            }
        }
    }
    const int col = q * 64 + lane;
    const float bb = (col < HID) ? b2[col] : 0.0f;
    __syncthreads();

#define WALK(mm, kb)                                                         \
    while (__popcll(mm) >= 4) {                                              \
        const int k0 = __builtin_ctzll(mm); mm &= mm - 1;                    \
        const int k1 = __builtin_ctzll(mm); mm &= mm - 1;                    \
        const int k2 = __builtin_ctzll(mm); mm &= mm - 1;                    \
        const int k3 = __builtin_ctzll(mm); mm &= mm - 1;                    \
        const float w0 = Wq[((kb) + k0) * 64 + lane];                        \
        const float w1 = Wq[((kb) + k1) * 64 + lane];                        \
        const float w2 = Wq[((kb) + k2) * 64 + lane];                        \
        const float w3 = Wq[((kb) + k3) * 64 + lane];                        \
        acc = acc + w0; acc = acc + w1; acc = acc + w2; acc = acc + w3;      \
    }                                                                        \
    while (mm) {                                                             \
        const int k0 = __builtin_ctzll(mm); mm &= mm - 1;                    \
        acc = acc + Wq[((kb) + k0) * 64 + lane];                             \
    }

    // preload spikes of this wave's first row
    const uint8_t* sr0 = s + (r0 + wave) * (long)HID;
    uint8_t c0v = sr0[lane];
    uint8_t c1v = sr0[64 + lane];
    uint8_t c2v = sr0[128 + lane];
    uint8_t c3v = (lane < 58) ? sr0[192 + lane] : (uint8_t)0;

    for (int rr = 0; rr < 32; ++rr) {
        const long row = r0 + wave + 4L * rr;
        // prefetch next row's spike bytes under this row's walk
        uint8_t n0 = 0, n1 = 0, n2 = 0, n3 = 0;
        if (rr < 31) {
            const uint8_t* sn = s + (row + 4) * (long)HID;
            n0 = sn[lane]; n1 = sn[64 + lane]; n2 = sn[128 + lane];
            n3 = (lane < 58) ? sn[192 + lane] : (uint8_t)0;
        }
        unsigned long long m0 = __ballot(c0v != 0);
        unsigned long long m1 = __ballot(c1v != 0);
        unsigned long long m2 = __ballot(c2v != 0);
        unsigned long long m3 = __ballot(c3v != 0);

        float acc = 0.0f;
        WALK(m0, 0)
        WALK(m1, 64)
        WALK(m2, 128)
        WALK(m3, 192)

        if (col < HID) cur[row * HID + col] = acc + bb;
        c0v = n0; c1v = n1; c2v = n2; c3v = n3;
    }
#undef WALK
}

// ---------------------------------------------------------------------------
// GEMM3: unchanged (small share of runtime).
// ---------------------------------------------------------------------------
__global__ __launch_bounds__(256) void gemm3_f32(
    const uint8_t* __restrict__ s,   // [M][250]
    const float* __restrict__ W3,    // [250][2]
    const float* __restrict__ b3,    // [2]
    float* __restrict__ cur3,        // [M][2]
    int M)
{
#pragma clang fp contract(off)
    __shared__ int wl[4][256];
    const int tid = threadIdx.x;
    const int wave = tid >> 6, lane = tid & 63;
    const long row = (long)blockIdx.x * 4 + wave;

    int base = 0;
    #pragma unroll
    for (int c = 0; c < 4; ++c) {
        const int k = c * 64 + lane;
        const bool sp = (k < HID) && s[row * HID + k];
        unsigned long long mask = __ballot(sp);
        if (sp) wl[wave][base + __popcll(mask & ((1ull << lane) - 1ull))] = k;
        base += __popcll(mask);      // wave-uniform
    }
    __syncthreads();

    if (lane < 2) {
        const int nact = base;
        float acc = 0.0f;
        for (int j = 0; j < nact; ++j)
            acc = acc + W3[wl[wave][j] * 2 + lane];
        cur3[row * 2 + lane] = acc + b3[lane];
    }
}

// ---------------------------------------------------------------------------
// Output scan (unchanged): writes spikes (f32 0/1) and mem_rec into d_out.
// ---------------------------------------------------------------------------
__global__ __launch_bounds__(256) void scan3_f32(
    const float* __restrict__ cur3,  // [Tc][1024]
    float* __restrict__ state,       // [1024]
    float* __restrict__ out,         // spikes @0, mem @OUT_HALF
    int t0, int Tc)
{
#pragma clang fp contract(off)
    const int n = blockIdx.x * 256 + threadIdx.x;   // grid = 4*256 == 1024
    float m = state[n];
    for (int t = 0; t < Tc; ++t) {
        const float c = cur3[(long)t * 1024 + n];
        const float reset = (m > 1.0f) ? 1.0f : 0.0f;
        float tmp = 0.9f * m; tmp = tmp + c; m = tmp - reset;
        const long o = (long)(t0 + t) * 1024 + n;
        out[o] = (m > 1.0f) ? 1.0f : 0.0f;
        out[OUT_HALF + o] = m;
    }
    state[n] = m;
}

// ---------------------------------------------------------------------------
extern "C" void kernel_launch(void* const* d_in, const int* in_sizes, int n_in,
                              void* d_out, int out_size, void* d_ws, size_t ws_size,
                              hipStream_t stream) {
    const float* x  = (const float*)d_in[0];
    const float* W1 = (const float*)d_in[1];
    const float* b1 = (const float*)d_in[2];
    const float* W2 = (const float*)d_in[3];
    const float* b2 = (const float*)d_in[4];
    const float* W3 = (const float*)d_in[5];
    const float* b3 = (const float*)d_in[6];
    float* out = (float*)d_out;

    char* w = (char*)d_ws;
    size_t off = 0;
    auto alloc = [&](size_t bytes) -> void* {
        void* p = (void*)(w + off);
        off = (off + bytes + 255) & ~(size_t)255;
        return p;
    };

    float* m1 = (float*)alloc((size_t)N1 * 4);      // 512,000 B
    float* m2 = (float*)alloc((size_t)N1 * 4);      // 512,000 B
    float* m3 = (float*)alloc(1024 * 4);            // 4,096 B
    const size_t states = off;                       // zeroed each call
    float* W1p = (float*)alloc(128 * 256 * 4);      // 131,072 B
    float* W2p = (float*)alloc(250 * 256 * 4);      // 256,000 B
    const size_t fixed = off;

    // chunk size from workspace: per-step = cur3(4K) + sbuf(125K) + cur(500K)
    const size_t perT = 4096 + 128000 + 512000;
    long tc_budget = ((long)ws_size - (long)fixed - 4096) / (long)perT;
    int Tc = (int)(tc_budget < 1 ? 1 : (tc_budget > T_TOTAL ? T_TOTAL : tc_budget));

    float*   cur3 = (float*)alloc((size_t)Tc * 4096);
    uint8_t* sbuf = (uint8_t*)alloc((size_t)Tc * 128000);
    float*   cur  = (float*)alloc((size_t)Tc * 512000);

    hipMemsetAsync(d_ws, 0, states, stream);   // zero membrane states
    pad_w<<<250, 256, 0, stream>>>(W1, W2, W1p, W2p);

    for (int t0 = 0; t0 < T_TOTAL; t0 += Tc) {
        const int tc = (T_TOTAL - t0 < Tc) ? (T_TOTAL - t0) : Tc;
        const int M = tc * BATCH;   // divisible by 512 -> by 128/64/16/4

        gemm1_v3<<<M / 64, 256, 0, stream>>>(x + (size_t)t0 * BATCH * NIN,
                                             W1p, b1, cur, M);
        scan_f32<<<N1 / 256, 256, 0, stream>>>(cur, sbuf, m1, tc);
        gemm2_v3<<<(M / 128) * 4, 256, 0, stream>>>(sbuf, W2p, b2, cur, M);
        scan_f32<<<N1 / 256, 256, 0, stream>>>(cur, sbuf, m2, tc);
        gemm3_f32<<<M / 4, 256, 0, stream>>>(sbuf, W3, b3, cur3, M);
        scan3_f32<<<4, 256, 0, stream>>>(cur3, m3, out, t0, tc);
    }
}

// Round 2
// 2189.466 us; speedup vs baseline: 1.3686x; 1.3686x over previous
//
#include <hip/hip_runtime.h>
#include <cstdint>

#define HID 250
#define NIN 128
#define BATCH 512
#define N1 (BATCH * HID)          // 128000 layer-1/2 neuron-chains
#define T_TOTAL 1000
#define OUT_HALF 1024000          // 1000*512*2 floats per output tensor

// ---------------------------------------------------------------------------
// pad_w: one-time prep. W1p[128][256], W2p[250][256] — column-padded copies
// (cols 250..255 zero) for branch-free 16B-aligned float4 loads.
// ---------------------------------------------------------------------------
__global__ __launch_bounds__(256) void pad_w(
    const float* __restrict__ W1, const float* __restrict__ W2,
    float* __restrict__ W1p, float* __restrict__ W2p)
{
    const int i = blockIdx.x * 256 + threadIdx.x;   // grid 250*256 = 64000
    if (i < 128 * 256) {
        const int k = i >> 8, c = i & 255;
        W1p[i] = (c < HID) ? W1[k * HID + c] : 0.0f;
    }
    if (i < 250 * 256) {
        const int k = i >> 8, c = i & 255;
        W2p[i] = (c < HID) ? W2[k * HID + c] : 0.0f;
    }
}

// ---------------------------------------------------------------------------
// GEMM1 v4: 128 rows x 256 cols per block (256 thr). Each thread: 8 rows x
// 16 cols = 128 acc. Per k: 2 broadcast ds_read_b128 (a), 4 aligned float4
// W loads, 128 FMAs — 2x the FMA per W-load vs v3, halved W/L2 traffic,
// 256 issue-cycles of FMA per wave per k to hide load latency under.
// Numerics: per output element single accumulator, fused fmaf, k ascending —
// bit-identical chain to v2/v3.
// ---------------------------------------------------------------------------
__global__ __launch_bounds__(256, 2) void gemm1_v4(
    const float* __restrict__ x,    // [M][128]
    const float* __restrict__ W1p,  // [128][256] padded
    const float* __restrict__ b1,   // [250]
    float* __restrict__ cur,        // [M][250]
    int M)
{
#pragma clang fp contract(off)
    __shared__ __align__(16) float xT[128 * 132];   // 67584 B -> 2 blocks/CU
    const int tid  = threadIdx.x;
    const int lane = tid & 63, wave = tid >> 6;
    const long rowBase = (long)blockIdx.x * 128;

    // stage x[rowBase..+128][0..128) transposed; LDS writes conflict-free
    const float* xb = x + rowBase * NIN;
    #pragma unroll
    for (int i = 0; i < 16; ++i) {
        const int rr  = i & 1;                 // row half
        const int kq  = (i >> 1) * 4 + wave;   // 0..31
        const int row = rr * 64 + lane;        // 0..127
        const float4 v = *(const float4*)(xb + (long)row * NIN + kq * 4);
        xT[(4 * kq + 0) * 132 + row] = v.x;
        xT[(4 * kq + 1) * 132 + row] = v.y;
        xT[(4 * kq + 2) * 132 + row] = v.z;
        xT[(4 * kq + 3) * 132 + row] = v.w;
    }
    __syncthreads();

    const int ri = tid >> 4;   // 0..15 -> rows 8ri..8ri+7
    const int ci = tid & 15;   // 0..15 -> col quads 64j + 4ci

    float acc[8][16];
    #pragma unroll
    for (int r = 0; r < 8; ++r)
        #pragma unroll
        for (int c = 0; c < 16; ++c) acc[r][c] = 0.0f;

    #pragma unroll 2
    for (int k = 0; k < NIN; ++k) {
        const float4 a0 = *(const float4*)&xT[k * 132 + 8 * ri];      // bcast
        const float4 a1 = *(const float4*)&xT[k * 132 + 8 * ri + 4];  // bcast
        const float* wr = W1p + (k << 8) + 4 * ci;
        const float4 wv0 = *(const float4*)(wr);
        const float4 wv1 = *(const float4*)(wr + 64);
        const float4 wv2 = *(const float4*)(wr + 128);
        const float4 wv3 = *(const float4*)(wr + 192);
        const float w[16] = {wv0.x, wv0.y, wv0.z, wv0.w,
                             wv1.x, wv1.y, wv1.z, wv1.w,
                             wv2.x, wv2.y, wv2.z, wv2.w,
                             wv3.x, wv3.y, wv3.z, wv3.w};
        const float av[8] = {a0.x, a0.y, a0.z, a0.w, a1.x, a1.y, a1.z, a1.w};
        #pragma unroll
        for (int r = 0; r < 8; ++r)
            #pragma unroll
            for (int c = 0; c < 16; ++c)
                acc[r][c] = __builtin_fmaf(av[r], w[c], acc[r][c]);
    }

    // epilogue: +bias (separately rounded), float2 stores (250 even -> 8B ok)
    #pragma unroll
    for (int j = 0; j < 4; ++j) {
        #pragma unroll
        for (int p = 0; p < 2; ++p) {
            const int cp = 64 * j + 4 * ci + 2 * p;
            if (cp < HID) {
                const float b0 = b1[cp], b1v = b1[cp + 1];
                #pragma unroll
                for (int r = 0; r < 8; ++r) {
                    const long row = rowBase + 8 * ri + r;
                    float2 o;
                    o.x = acc[r][4*j + 2*p]     + b0;
                    o.y = acc[r][4*j + 2*p + 1] + b1v;
                    *(float2*)(cur + row * HID + cp) = o;
                }
            }
        }
    }
}

// ---------------------------------------------------------------------------
// LIF scan layers 1/2: unroll x8, loads batched ahead of the dependent
// recurrence (deeper MLP). Arithmetic per element identical.
// ---------------------------------------------------------------------------
__global__ __launch_bounds__(256) void scan_f32(
    const float* __restrict__ cur,   // [Tc][N1]
    uint8_t* __restrict__ spk,       // [Tc][N1]
    float* __restrict__ state,       // [N1]
    int Tc)
{
#pragma clang fp contract(off)
    const int n = blockIdx.x * 256 + threadIdx.x;   // grid = 500*256 == N1
    float m = state[n];
    int t = 0;
    for (; t + 8 <= Tc; t += 8) {
        const long base = (long)t * N1 + n;
        float c[8];
        #pragma unroll
        for (int u = 0; u < 8; ++u) c[u] = cur[base + (long)u * N1];
        #pragma unroll
        for (int u = 0; u < 8; ++u) {
            const float r = (m > 1.0f) ? 1.0f : 0.0f;
            float tmp = 0.9f * m; tmp = tmp + c[u]; m = tmp - r;
            spk[base + (long)u * N1] = (m > 1.0f) ? (uint8_t)1 : (uint8_t)0;
        }
    }
    for (; t < Tc; ++t) {
        const long base = (long)t * N1 + n;
        const float c = cur[base];
        const float r = (m > 1.0f) ? 1.0f : 0.0f;
        float tmp = 0.9f * m; tmp = tmp + c; m = tmp - r;
        spk[base] = (m > 1.0f) ? (uint8_t)1 : (uint8_t)0;
    }
    state[n] = m;
}

// ---------------------------------------------------------------------------
// GEMM2 v4: 32-col LDS chunk (32 KB -> 4 blocks/CU of 512 thr = 32 waves/CU,
// ~4x the concurrency of v3), 2 rows per wave walking the UNION spike mask:
// lanes = {row a, row b} x 32 cols. Per union-k: one broadcast ds_read_b32
// (bank-conflict-free: word = kk*32 + c32 -> bank c32) + cndmask-add.
// Numerics: member adds happen in ascending-k order with acc + w; non-member
// union ks add +0.0f which is bit-exact identity (acc never -0) — per-element
// chain identical to the list-walk version.
// ---------------------------------------------------------------------------
__global__ __launch_bounds__(512, 4) void gemm2_v4(
    const uint8_t* __restrict__ s,   // [M][250] spikes 0/1
    const float* __restrict__ W2p,   // [250][256] padded
    const float* __restrict__ b2,    // [250]
    float* __restrict__ cur,         // [M][250]
    int M)
{
#pragma clang fp contract(off)
    __shared__ __align__(16) float Wq[250 * 32];   // 32000 B
    const int tid  = threadIdx.x;
    const int lane = tid & 63, wave = tid >> 6;    // wave 0..7
    const int q    = blockIdx.x & 7;               // cols 32q..32q+31
    const long r0  = (long)(blockIdx.x >> 3) * 128;
    const int c32  = lane & 31;
    const int half = lane >> 5;                    // 0 -> row a, 1 -> row b

    // stage chunk: Wq[k][c] = W2p[k][32q + c]; 2000 float4s over 512 thr
    {
        const float* src = W2p + q * 32;
        #pragma unroll
        for (int i = 0; i < 4; ++i) {
            const int idx = i * 512 + tid;         // 0..2047
            if (idx < 2000) {
                const int k = idx >> 3, c4 = (idx & 7) * 4;
                *(float4*)&Wq[k * 32 + c4] = *(const float4*)(src + k * 256 + c4);
            }
        }
    }
    const int col = q * 32 + c32;
    const float bb = (col < HID) ? b2[col] : 0.0f;
    __syncthreads();

    // 8 row-pairs per wave: block covers rows r0 .. r0+127
    for (int p = 0; p < 8; ++p) {
        const long ra = r0 + wave * 16 + 2 * p;
        const long rb = ra + 1;
        const uint8_t* pa = s + ra * HID;
        const uint8_t* pb = s + rb * HID;
        unsigned long long ma[4], mb[4];
        #pragma unroll
        for (int c = 0; c < 4; ++c) {
            const int k = c * 64 + lane;
            ma[c] = __ballot((k < HID) && pa[k]);
            mb[c] = __ballot((k < HID) && pb[k]);
        }
        float acc = 0.0f;
        #pragma unroll
        for (int c = 0; c < 4; ++c) {
            unsigned long long mu = ma[c] | mb[c];          // uniform
            const unsigned long long msel = half ? mb[c] : ma[c];
            while (mu) {
                const int k = __builtin_ctzll(mu);
                mu &= mu - 1;
                const float wv = Wq[(c * 64 + k) * 32 + c32];
                acc = acc + (((msel >> k) & 1ull) ? wv : 0.0f);
            }
        }
        const long row = half ? rb : ra;
        if (col < HID) cur[row * HID + col] = acc + bb;
    }
}

// ---------------------------------------------------------------------------
// GEMM3: unchanged (small share of runtime).
// ---------------------------------------------------------------------------
__global__ __launch_bounds__(256) void gemm3_f32(
    const uint8_t* __restrict__ s,   // [M][250]
    const float* __restrict__ W3,    // [250][2]
    const float* __restrict__ b3,    // [2]
    float* __restrict__ cur3,        // [M][2]
    int M)
{
#pragma clang fp contract(off)
    __shared__ int wl[4][256];
    const int tid = threadIdx.x;
    const int wave = tid >> 6, lane = tid & 63;
    const long row = (long)blockIdx.x * 4 + wave;

    int base = 0;
    #pragma unroll
    for (int c = 0; c < 4; ++c) {
        const int k = c * 64 + lane;
        const bool sp = (k < HID) && s[row * HID + k];
        unsigned long long mask = __ballot(sp);
        if (sp) wl[wave][base + __popcll(mask & ((1ull << lane) - 1ull))] = k;
        base += __popcll(mask);      // wave-uniform
    }
    __syncthreads();

    if (lane < 2) {
        const int nact = base;
        float acc = 0.0f;
        for (int j = 0; j < nact; ++j)
            acc = acc + W3[wl[wave][j] * 2 + lane];
        cur3[row * 2 + lane] = acc + b3[lane];
    }
}

// ---------------------------------------------------------------------------
// Output scan v2: only 1024 threads exist -> per-thread pipelining is the
// only latency hiding. Batch 8 cur3 loads ahead of the dependent recurrence.
// ---------------------------------------------------------------------------
__global__ __launch_bounds__(256) void scan3_f32(
    const float* __restrict__ cur3,  // [Tc][1024]
    float* __restrict__ state,       // [1024]
    float* __restrict__ out,         // spikes @0, mem @OUT_HALF
    int t0, int Tc)
{
#pragma clang fp contract(off)
    const int n = blockIdx.x * 256 + threadIdx.x;   // grid = 4*256 == 1024
    float m = state[n];
    int t = 0;
    for (; t + 8 <= Tc; t += 8) {
        float c[8];
        #pragma unroll
        for (int u = 0; u < 8; ++u) c[u] = cur3[(long)(t + u) * 1024 + n];
        #pragma unroll
        for (int u = 0; u < 8; ++u) {
            const float reset = (m > 1.0f) ? 1.0f : 0.0f;
            float tmp = 0.9f * m; tmp = tmp + c[u]; m = tmp - reset;
            const long o = (long)(t0 + t + u) * 1024 + n;
            out[o] = (m > 1.0f) ? 1.0f : 0.0f;
            out[OUT_HALF + o] = m;
        }
    }
    for (; t < Tc; ++t) {
        const float c = cur3[(long)t * 1024 + n];
        const float reset = (m > 1.0f) ? 1.0f : 0.0f;
        float tmp = 0.9f * m; tmp = tmp + c; m = tmp - reset;
        const long o = (long)(t0 + t) * 1024 + n;
        out[o] = (m > 1.0f) ? 1.0f : 0.0f;
        out[OUT_HALF + o] = m;
    }
    state[n] = m;
}

// ---------------------------------------------------------------------------
extern "C" void kernel_launch(void* const* d_in, const int* in_sizes, int n_in,
                              void* d_out, int out_size, void* d_ws, size_t ws_size,
                              hipStream_t stream) {
    const float* x  = (const float*)d_in[0];
    const float* W1 = (const float*)d_in[1];
    const float* b1 = (const float*)d_in[2];
    const float* W2 = (const float*)d_in[3];
    const float* b2 = (const float*)d_in[4];
    const float* W3 = (const float*)d_in[5];
    const float* b3 = (const float*)d_in[6];
    float* out = (float*)d_out;

    char* w = (char*)d_ws;
    size_t off = 0;
    auto alloc = [&](size_t bytes) -> void* {
        void* p = (void*)(w + off);
        off = (off + bytes + 255) & ~(size_t)255;
        return p;
    };

    float* m1 = (float*)alloc((size_t)N1 * 4);      // 512,000 B
    float* m2 = (float*)alloc((size_t)N1 * 4);      // 512,000 B
    float* m3 = (float*)alloc(1024 * 4);            // 4,096 B
    const size_t states = off;                       // zeroed each call
    float* W1p = (float*)alloc(128 * 256 * 4);      // 131,072 B
    float* W2p = (float*)alloc(250 * 256 * 4);      // 256,000 B
    const size_t fixed = off;

    // chunk size from workspace: per-step = cur3(4K) + sbuf(125K) + cur(500K)
    const size_t perT = 4096 + 128000 + 512000;
    long tc_budget = ((long)ws_size - (long)fixed - 4096) / (long)perT;
    int Tc = (int)(tc_budget < 1 ? 1 : (tc_budget > T_TOTAL ? T_TOTAL : tc_budget));

    float*   cur3 = (float*)alloc((size_t)Tc * 4096);
    uint8_t* sbuf = (uint8_t*)alloc((size_t)Tc * 128000);
    float*   cur  = (float*)alloc((size_t)Tc * 512000);

    hipMemsetAsync(d_ws, 0, states, stream);   // zero membrane states
    pad_w<<<250, 256, 0, stream>>>(W1, W2, W1p, W2p);

    for (int t0 = 0; t0 < T_TOTAL; t0 += Tc) {
        const int tc = (T_TOTAL - t0 < Tc) ? (T_TOTAL - t0) : Tc;
        const int M = tc * BATCH;   // divisible by 512 -> by 128/64/16/4

        gemm1_v4<<<M / 128, 256, 0, stream>>>(x + (size_t)t0 * BATCH * NIN,
                                              W1p, b1, cur, M);
        scan_f32<<<N1 / 256, 256, 0, stream>>>(cur, sbuf, m1, tc);
        gemm2_v4<<<(M / 128) * 8, 512, 0, stream>>>(sbuf, W2p, b2, cur, M);
        scan_f32<<<N1 / 256, 256, 0, stream>>>(cur, sbuf, m2, tc);
        gemm3_f32<<<M / 4, 256, 0, stream>>>(sbuf, W3, b3, cur3, M);
        scan3_f32<<<4, 256, 0, stream>>>(cur3, m3, out, t0, tc);
    }
}